// Round 15
// baseline (725.126 us; speedup 1.0000x reference)
//
#include <hip/hip_runtime.h>
#include <hip/hip_bf16.h>
#include <math.h>
#include <stdint.h>

#define T_ 1024
#define H_ 2048
#define NH_ 16
#define NKV_ 4
#define HD_ 128
#define E_ 32
#define TOPK_ 4
#define I_ 1024
#define QKVN_ 3072
#define EPS_ 1e-6f
#define THETA_ 600000.0f
#define SCALE_ 0.08838834764831845f
#define NMOE_ 3072

typedef unsigned short u16;
typedef u16 u16x4 __attribute__((ext_vector_type(4)));
typedef u16 u16x8 __attribute__((ext_vector_type(8)));
typedef __bf16 bf16x8 __attribute__((ext_vector_type(8)));
typedef float f32x4 __attribute__((ext_vector_type(4)));

__device__ __forceinline__ u16 f2b(float f) {
  unsigned u = __builtin_bit_cast(unsigned, f);
  u += 0x7FFFu + ((u >> 16) & 1u);
  return (u16)(u >> 16);
}
__device__ __forceinline__ float b2f(u16 x) {
  unsigned u = ((unsigned)x) << 16;
  return __builtin_bit_cast(float, u);
}
__device__ __forceinline__ int s2(int i) { return (i ^ (i >> 2)) & 3; }
__device__ __forceinline__ int sw3(int i) { return (i ^ (i >> 3)) & 7; }

__device__ __forceinline__ void gload16(const void* g, void* l) {
  __builtin_amdgcn_global_load_lds(
      reinterpret_cast<const __attribute__((address_space(1))) unsigned int*>(
          reinterpret_cast<uintptr_t>(g)),
      reinterpret_cast<__attribute__((address_space(3))) unsigned int*>(
          reinterpret_cast<uintptr_t>(l)),
      16, 0, 0);
}

// ---------------------------------------------------------------------------
// Fused MoE grouped GEMM + dense tail. M64 x N64 x BK64, 512 threads,
// 2-buffer LDS (32 KB), 4 blocks/CU. Inner loop identical to R14 (best).
// Blocks idx <  NMOE_: MoE via compact tpre mapping (t=idx>>5, xx=idx&31).
// Blocks idx >= NMOE_: dense tail (512 blocks, 16m x 32n of 64):
//   EPI0: gub = h2b @ ws_gu.T  (bf16 store)
//   EPI1: out += actsh @ ws_dn.T (atomicAdd; out pre-initialized to x1)
// MoE EPI0: fused up (xx<16 -> w1/O1, else w3/O2), plain f32 store.
// MoE EPI1: down, atomicAdd slotw*acc into O1[token] (O1 = out).
// ---------------------------------------------------------------------------
template<int EPI, bool GATHER>
__global__ __launch_bounds__(512, 8) void moe_gemm_k(
    const u16* __restrict__ A, const float* __restrict__ B, const float* __restrict__ B2,
    float* __restrict__ O1, float* __restrict__ O2,
    int NW, int lda, int ldb, int K,
    const int* __restrict__ eoff, const int* __restrict__ tpre,
    const int* __restrict__ slots, const float* __restrict__ slotw, long long sBz,
    const u16* __restrict__ Ad, const float* __restrict__ Bd,
    u16* __restrict__ Od_b, float* __restrict__ Od_f)
{
  __shared__ u16 As[2][64 * 64];
  __shared__ u16 Bs[2][64 * 64];

  const int idx = blockIdx.x;
  const bool tail = idx >= NMOE_;

  int m0, n0, goff = 0, Mloc = T_, e = 0;
  const float* Bp = nullptr;
  float* Op = nullptr;
  if (tail) {
    int did = idx - NMOE_;          // 0..511
    m0 = (did >> 5) * 64;
    n0 = (did & 31) * 64;
  } else {
    const int t = idx >> 5;
    const int xx = idx & 31;
    if (t >= tpre[E_]) return;
    int lo = 0, hi = E_;
    while (hi - lo > 1) { int mid = (lo + hi) >> 1; if (tpre[mid] <= t) lo = mid; else hi = mid; }
    e = lo;
    const int mb = t - tpre[e];
    goff = eoff[e];
    Mloc = eoff[e + 1] - goff;
    m0 = mb * 64;
    if constexpr (EPI == 0) {
      int wsel = xx >> 4;
      n0 = (xx & 15) * 64;
      Bp = (wsel ? B2 : B) + (long long)e * sBz;
      Op = wsel ? O2 : O1;
    } else {
      n0 = xx * 64;
      Bp = B + (long long)e * sBz;
      Op = O1;
    }
  }

  const int tid = threadIdx.x;
  const int lane = tid & 63;
  const int wv = tid >> 6;
  const int wm = wv >> 2, wn = wv & 3;
  const int kg = lane >> 4;
  const int cr = lane & 15;

  // A staging base (both paths: row-major bf16, stride lda)
  const u16* Abase;
  {
    int r = wv * 8 + (lane >> 3);
    if (tail) {
      Abase = Ad + (long long)(m0 + r) * lda + (((lane & 7) ^ sw3(r)) << 3);
    } else {
      int rr = m0 + r;
      if (rr > Mloc - 1) rr = Mloc - 1;
      long long grow = GATHER ? (long long)slots[goff + rr] : (long long)(goff + rr);
      if (GATHER) grow = (long long)slots[goff + rr];
      else grow = (long long)(goff + rr);
      // A for MoE non-gather path is already offset per-expert via goff row
      Abase = (GATHER ? A : A) + grow * (long long)lda + (((lane & 7) ^ sw3(r)) << 3);
    }
  }
  auto stageA = [&](int bf, int k0) {
    gload16(Abase + k0, &As[bf][wv * 512]);
  };

  // B staging: thread -> n = tid&63, k-chunk kc = tid>>6 (8 k each)
  const int bn = tid & 63;
  const int kc = tid >> 6;
  const float* Bbase;
  if (tail) {
    Bbase = Bd + (long long)(n0 + bn) * K + (kc << 3);   // [n][k], contiguous k
  } else {
    Bbase = Bp + (long long)(kc << 3) * ldb + n0 + bn;   // [k][n], strided
  }
  const int bws = bn * 64 + ((kc ^ sw3(bn)) << 3);

  float br[8];
  auto loadB = [&](int k0) {
    if (tail) {
      const float* p = Bbase + k0;
      float4 a = *(const float4*)p;
      float4 b = *(const float4*)(p + 4);
      br[0] = a.x; br[1] = a.y; br[2] = a.z; br[3] = a.w;
      br[4] = b.x; br[5] = b.y; br[6] = b.z; br[7] = b.w;
    } else {
      const float* p = Bbase + (long long)k0 * ldb;
      #pragma unroll
      for (int j = 0; j < 8; ++j) br[j] = p[(long long)j * ldb];
    }
  };
  auto writeB = [&](int bf) {
    u16x8 o;
    #pragma unroll
    for (int j = 0; j < 8; ++j) o[j] = f2b(br[j]);
    *(u16x8*)(&Bs[bf][bws]) = o;
  };

  f32x4 acc[2];
  acc[0] = f32x4{0.f, 0.f, 0.f, 0.f};
  acc[1] = f32x4{0.f, 0.f, 0.f, 0.f};

  int aoff[2], asw[2];
  #pragma unroll
  for (int m = 0; m < 2; ++m) {
    int r = wm * 32 + m * 16 + cr;
    aoff[m] = r * 64; asw[m] = sw3(r);
  }
  const int bc = wn * 16 + cr;
  const int boff = bc * 64;
  const int bsw = sw3(bc);

  auto mfma_step = [&](int bf) {
    const u16* Ap = &As[bf][0];
    const u16* Bq = &Bs[bf][0];
    #pragma unroll
    for (int sub = 0; sub < 2; ++sub) {
      int ck = kg + sub * 4;
      bf16x8 af0 = __builtin_bit_cast(bf16x8, *(const u16x8*)(Ap + aoff[0] + ((ck ^ asw[0]) << 3)));
      bf16x8 af1 = __builtin_bit_cast(bf16x8, *(const u16x8*)(Ap + aoff[1] + ((ck ^ asw[1]) << 3)));
      bf16x8 bfr = __builtin_bit_cast(bf16x8, *(const u16x8*)(Bq + boff + ((ck ^ bsw) << 3)));
      acc[0] = __builtin_amdgcn_mfma_f32_16x16x32_bf16(af0, bfr, acc[0], 0, 0, 0);
      acc[1] = __builtin_amdgcn_mfma_f32_16x16x32_bf16(af1, bfr, acc[1], 0, 0, 0);
    }
  };

  loadB(0);
  stageA(0, 0);
  writeB(0);
  __syncthreads();

  int buf = 0;
  for (int ks = 0; ks < K; ks += 64) {
    bool more = (ks + 64) < K;
    if (more) { loadB(ks + 64); stageA(buf ^ 1, ks + 64); }
    mfma_step(buf);
    if (more) writeB(buf ^ 1);
    __syncthreads();
    buf ^= 1;
  }

  const int rq = lane >> 4;
  #pragma unroll
  for (int m = 0; m < 2; ++m) {
    #pragma unroll
    for (int j = 0; j < 4; ++j) {
      int row = m0 + wm * 32 + m * 16 + rq * 4 + j;
      int col = n0 + wn * 16 + cr;
      if (tail) {
        if constexpr (EPI == 0) {
          Od_b[(long long)row * 2048 + col] = f2b(acc[m][j]);
        } else {
          atomicAdd(Od_f + (long long)row * 2048 + col, acc[m][j]);
        }
      } else {
        if (row >= Mloc) continue;
        if constexpr (EPI == 0) {
          Op[(long long)(goff + row) * NW + col] = acc[m][j];
        } else {
          int tok = slots[goff + row];
          float wgt = slotw[goff + row];
          atomicAdd(Op + (long long)tok * NW + col, wgt * acc[m][j]);
        }
      }
    }
  }
}

// ---------------------------------------------------------------------------
// Dense GEMM: M64 x N128 x BK32, 512 threads.
// EPI: 0 bf16 | 1 bf16*alpha | 2 f32 res1+acc | 5 f32 res1+acc dual-store.
// ---------------------------------------------------------------------------
template<typename TB, int EPI, int CAUSAL>
__global__ __launch_bounds__(512, 8) void dense_gemm_k(
    const u16* __restrict__ A, const TB* __restrict__ B,
    u16* __restrict__ Cb, float* __restrict__ Cf, float* __restrict__ Cf2,
    const float* __restrict__ res1,
    int K, int lda, int ldb, int ldc, float alpha,
    long long sAz, long long sBz, long long sCz, int bdivz)
{
  __shared__ u16 As[2][64 * 32];
  __shared__ u16 Bs[2][128 * 32];

  const int m0 = blockIdx.y * 64;
  const int n0 = blockIdx.x * 128;
  if (CAUSAL == 1 && n0 > m0 + 63) return;
  const long long z = blockIdx.z;
  const u16* Ae = A + z * sAz;
  const TB* Be = B + (long long)(z / bdivz) * sBz;
  u16* Cwb = Cb ? Cb + z * sCz : nullptr;

  int kend = K;
  if (CAUSAL == 2) { int ke = m0 + 64; if (ke < kend) kend = ke; }

  const int tid = threadIdx.x;
  const int lane = tid & 63;
  const int wv = tid >> 6;
  const int wm = wv >> 2, wn = wv & 3;

  const u16* Abase = nullptr;
  if (wv < 4) {
    int r = wv * 16 + (lane >> 2);
    Abase = Ae + (long long)(m0 + r) * lda + (((lane & 3) ^ s2(r)) << 3);
  }
  auto stageA = [&](int bf, int k0) {
    if (wv < 4) gload16(Abase + k0, &As[bf][wv * 512]);
  };

  const u16* Bu16base = nullptr;
  const float* Bf32base = nullptr;
  int bws = 0;
  if constexpr (sizeof(TB) == 2) {
    int r = wv * 16 + (lane >> 2);
    Bu16base = (const u16*)Be + (long long)(n0 + r) * ldb + (((lane & 3) ^ s2(r)) << 3);
  } else {
    int bn = tid >> 2, bkq = tid & 3;
    Bf32base = (const float*)Be + (long long)(n0 + bn) * ldb + (bkq << 3);
    bws = bn * 32 + ((bkq ^ s2(bn)) << 3);
  }
  float br[8];
  auto loadB = [&](int k0) {
    const float* p = Bf32base + k0;
    float4 a = *(const float4*)p;
    float4 b = *(const float4*)(p + 4);
    br[0] = a.x; br[1] = a.y; br[2] = a.z; br[3] = a.w;
    br[4] = b.x; br[5] = b.y; br[6] = b.z; br[7] = b.w;
  };
  auto writeB = [&](int bf) {
    u16x8 o;
    #pragma unroll
    for (int j = 0; j < 8; ++j) o[j] = f2b(br[j]);
    *(u16x8*)(&Bs[bf][bws]) = o;
  };
  auto stageBu = [&](int bf, int k0) {
    gload16(Bu16base + k0, &Bs[bf][wv * 512]);
  };

  f32x4 acc[2][2];
  #pragma unroll
  for (int m = 0; m < 2; ++m)
    #pragma unroll
    for (int n = 0; n < 2; ++n)
      acc[m][n] = f32x4{0.f, 0.f, 0.f, 0.f};

  const int kg = lane >> 4;
  const int cr = lane & 15;

  int aoff[2], boff[2];
  #pragma unroll
  for (int m = 0; m < 2; ++m) {
    int r = wm * 32 + m * 16 + cr;
    aoff[m] = r * 32 + ((kg ^ s2(r)) << 3);
  }
  #pragma unroll
  for (int n = 0; n < 2; ++n) {
    int c = wn * 32 + n * 16 + cr;
    boff[n] = c * 32 + ((kg ^ s2(c)) << 3);
  }

  if constexpr (sizeof(TB) == 4) {
    loadB(0); stageA(0, 0); writeB(0);
  } else {
    stageA(0, 0); stageBu(0, 0);
  }
  __syncthreads();

  int buf = 0;
  for (int ks = 0; ks < kend; ks += 32) {
    bool more = (ks + 32) < kend;
    if (more) {
      if constexpr (sizeof(TB) == 4) { loadB(ks + 32); stageA(buf ^ 1, ks + 32); }
      else { stageA(buf ^ 1, ks + 32); stageBu(buf ^ 1, ks + 32); }
    }
    const u16* Ap = &As[buf][0];
    const u16* Bq = &Bs[buf][0];
    bf16x8 af[2], bfr[2];
    #pragma unroll
    for (int m = 0; m < 2; ++m)
      af[m] = __builtin_bit_cast(bf16x8, *(const u16x8*)(Ap + aoff[m]));
    #pragma unroll
    for (int n = 0; n < 2; ++n)
      bfr[n] = __builtin_bit_cast(bf16x8, *(const u16x8*)(Bq + boff[n]));
    #pragma unroll
    for (int m = 0; m < 2; ++m)
      #pragma unroll
      for (int n = 0; n < 2; ++n)
        acc[m][n] = __builtin_amdgcn_mfma_f32_16x16x32_bf16(af[m], bfr[n], acc[m][n], 0, 0, 0);
    if constexpr (sizeof(TB) == 4) { if (more) writeB(buf ^ 1); }
    __syncthreads();
    buf ^= 1;
  }

  const int rq = lane >> 4;
  #pragma unroll
  for (int m = 0; m < 2; ++m) {
    #pragma unroll
    for (int j = 0; j < 4; ++j) {
      int row = m0 + wm * 32 + m * 16 + rq * 4 + j;
      #pragma unroll
      for (int n = 0; n < 2; ++n) {
        int col = n0 + wn * 32 + n * 16 + cr;
        float v = acc[m][n][j];
        long long o = (long long)row * ldc + col;
        if constexpr (EPI == 0) {
          Cwb[o] = f2b(v);
        } else if constexpr (EPI == 1) {
          Cwb[o] = f2b(v * alpha);
        } else if constexpr (EPI == 2) {
          Cf[o] = res1[o] + v;
        } else {
          float val = res1[o] + v;
          Cf[o] = val;
          Cf2[o] = val;
        }
      }
    }
  }
}

// ---------------------------------------------------------------------------
__global__ __launch_bounds__(256) void vtrans_k(const u16* __restrict__ v_r,
                                                u16* __restrict__ v_t) {
  __shared__ u16 t[64][72];
  int kv = blockIdx.z;
  int s0 = blockIdx.x * 64, d0 = blockIdx.y * 64;
  int tid = threadIdx.x;
  int sr = tid >> 2, dq = (tid & 3) * 16;
  const u16* src = v_r + ((long long)kv * T_ + s0 + sr) * HD_ + d0 + dq;
  *(u16x8*)&t[sr][dq] = *(const u16x8*)src;
  *(u16x8*)&t[sr][dq + 8] = *(const u16x8*)(src + 8);
  __syncthreads();
  int dr = tid >> 2, sq = (tid & 3) * 16;
  u16* dst = v_t + ((long long)kv * HD_ + d0 + dr) * T_ + s0 + sq;
  u16x8 o0, o1;
  #pragma unroll
  for (int j = 0; j < 8; ++j) { o0[j] = t[sq + j][dr]; o1[j] = t[sq + 8 + j][dr]; }
  *(u16x8*)dst = o0;
  *(u16x8*)(dst + 8) = o1;
}

// ---------------------------------------------------------------------------
__global__ __launch_bounds__(256) void rmsnorm_k(const float* __restrict__ x,
                                                 const float* __restrict__ w,
                                                 u16* __restrict__ outb,
                                                 float* __restrict__ outf) {
  int t = blockIdx.x;
  int tid = threadIdx.x;
  const float* xr = x + (long long)t * H_;
  float4 a = *(const float4*)(xr + tid * 8);
  float4 b = *(const float4*)(xr + tid * 8 + 4);
  float ss = a.x * a.x + a.y * a.y + a.z * a.z + a.w * a.w +
             b.x * b.x + b.y * b.y + b.z * b.z + b.w * b.w;
  #pragma unroll
  for (int o = 32; o; o >>= 1) ss += __shfl_down(ss, o);
  __shared__ float red[4];
  if ((tid & 63) == 0) red[tid >> 6] = ss;
  __syncthreads();
  float sc = rsqrtf((red[0] + red[1] + red[2] + red[3]) * (1.0f / H_) + EPS_);
  float vo[8] = {a.x, a.y, a.z, a.w, b.x, b.y, b.z, b.w};
  const float* wr = w + tid * 8;
  u16x8 ob;
  #pragma unroll
  for (int q = 0; q < 8; ++q) {
    float val = vo[q] * sc * wr[q];
    ob[q] = f2b(val);
    if (outf) outf[(long long)t * H_ + tid * 8 + q] = val;
  }
  *(u16x8*)(outb + (long long)t * H_ + tid * 8) = ob;
}

__global__ __launch_bounds__(256) void rope_k(const u16* __restrict__ qkv,
                                              const int* __restrict__ pos,
                                              u16* __restrict__ q_r,
                                              u16* __restrict__ k_r,
                                              u16* __restrict__ v_r) {
  int t = blockIdx.x;
  int tid = threadIdx.x;
  float p = (float)pos[t];
  const u16* row = qkv + (long long)t * QKVN_;
  const float cfac = logf(THETA_) * (1.0f / 64.0f);
  #pragma unroll
  for (int it = 0; it < 4; ++it) {
    int item = it * 256 + tid;
    int h = item >> 6, d = item & 63;
    float inv = expf(-cfac * (float)d);
    float ang = p * inv;
    float c = cosf(ang), s = sinf(ang);
    float x1v = b2f(row[h * 128 + d]);
    float x2v = b2f(row[h * 128 + 64 + d]);
    u16* dst = q_r + ((long long)h * T_ + t) * HD_;
    dst[d] = f2b(x1v * c - x2v * s);
    dst[d + 64] = f2b(x1v * s + x2v * c);
  }
  {
    int item = tid;
    int kv = item >> 6, d = item & 63;
    float inv = expf(-cfac * (float)d);
    float ang = p * inv;
    float c = cosf(ang), s = sinf(ang);
    float x1v = b2f(row[NH_ * HD_ + kv * 128 + d]);
    float x2v = b2f(row[NH_ * HD_ + kv * 128 + 64 + d]);
    u16* dst = k_r + ((long long)kv * T_ + t) * HD_;
    dst[d] = f2b(x1v * c - x2v * s);
    dst[d + 64] = f2b(x1v * s + x2v * c);
  }
  #pragma unroll
  for (int it = 0; it < 2; ++it) {
    int item = it * 256 + tid;
    int kv = item >> 7, d = item & 127;
    v_r[((long long)kv * T_ + t) * HD_ + d] = row[(NH_ + NKV_) * HD_ + kv * 128 + d];
  }
}

__global__ __launch_bounds__(64) void softmax_k(u16* __restrict__ P) {
  int r = blockIdx.x;
  int h = r >> 10, i = r & 1023;
  u16* row = P + ((long long)h * T_ + i) * T_;
  int lane = threadIdx.x;
  int n = i + 1;
  float vals[16];
  float mx = -1e30f;
  #pragma unroll
  for (int it = 0; it < 16; ++it) {
    int j = it * 64 + lane;
    float s = (j < n) ? b2f(row[j]) : -1e30f;
    vals[it] = s;
    mx = fmaxf(mx, s);
  }
  #pragma unroll
  for (int o = 32; o; o >>= 1) mx = fmaxf(mx, __shfl_xor(mx, o));
  float sum = 0.f;
  #pragma unroll
  for (int it = 0; it < 16; ++it) {
    int j = it * 64 + lane;
    float e = (j < n) ? __expf(vals[it] - mx) : 0.f;
    vals[it] = e;
    sum += e;
  }
  #pragma unroll
  for (int o = 32; o; o >>= 1) sum += __shfl_xor(sum, o);
  float inv = 1.f / sum;
  #pragma unroll
  for (int it = 0; it < 16; ++it) {
    int j = it * 64 + lane;
    row[j] = f2b(vals[it] * inv);
  }
}

__global__ __launch_bounds__(256) void router2_k(const float* __restrict__ h2,
                                                 const float* __restrict__ wr,
                                                 float* __restrict__ logits) {
  __shared__ float hrow[H_];
  int t = blockIdx.x;
  int tid = threadIdx.x;
  float4 a = *(const float4*)(h2 + (long long)t * H_ + tid * 8);
  float4 b = *(const float4*)(h2 + (long long)t * H_ + tid * 8 + 4);
  *(float4*)&hrow[tid * 8] = a;
  *(float4*)&hrow[tid * 8 + 4] = b;
  __syncthreads();
  int wv = tid >> 6, lane = tid & 63;
  #pragma unroll
  for (int ei = 0; ei < 8; ++ei) {
    int e = wv * 8 + ei;
    const float* wrow = wr + (long long)e * H_;
    float s = 0.f;
    #pragma unroll
    for (int it = 0; it < 8; ++it) {
      int k = it * 256 + lane * 4;
      float4 w4 = *(const float4*)(wrow + k);
      s += hrow[k] * w4.x + hrow[k + 1] * w4.y + hrow[k + 2] * w4.z + hrow[k + 3] * w4.w;
    }
    #pragma unroll
    for (int o = 32; o; o >>= 1) s += __shfl_xor(s, o);
    if (lane == 0) logits[t * E_ + e] = s;
  }
}

__global__ __launch_bounds__(256) void topk_k(const float* __restrict__ logits,
                                              int* __restrict__ topi,
                                              float* __restrict__ topw) {
  int t = blockIdx.x * 256 + threadIdx.x;
  if (t >= T_) return;
  float l[E_];
  #pragma unroll
  for (int e = 0; e < E_; ++e) l[e] = logits[t * E_ + e];
  int sel[TOPK_];
  float sv[TOPK_];
  unsigned used = 0;
  for (int j = 0; j < TOPK_; ++j) {
    float best = -1e30f;
    int bi = 0;
    for (int e = 0; e < E_; ++e) {
      if (used & (1u << e)) continue;
      if (l[e] > best) { best = l[e]; bi = e; }
    }
    used |= 1u << bi;
    sel[j] = bi;
    sv[j] = best;
  }
  float mx = sv[0];
  float s = 0.f;
  #pragma unroll
  for (int j = 0; j < TOPK_; ++j) { sv[j] = __expf(sv[j] - mx); s += sv[j]; }
  float inv = 1.f / s;
  #pragma unroll
  for (int j = 0; j < TOPK_; ++j) {
    topi[t * TOPK_ + j] = sel[j];
    topw[t * TOPK_ + j] = sv[j] * inv;
  }
}

__global__ __launch_bounds__(256) void hist_k(const int* __restrict__ topi, int* __restrict__ cnt) {
  int idx = blockIdx.x * 256 + threadIdx.x;
  if (idx < T_ * TOPK_) atomicAdd(&cnt[topi[idx]], 1);
}

__global__ __launch_bounds__(64) void scan_k(const int* __restrict__ cnt,
                                             int* __restrict__ eoff,
                                             int* __restrict__ cursor,
                                             int* __restrict__ tpre) {
  if (threadIdx.x == 0) {
    int s = 0, tt = 0;
    for (int e = 0; e < E_; ++e) {
      eoff[e] = s; cursor[e] = s; tpre[e] = tt;
      tt += (cnt[e] + 63) >> 6;
      s += cnt[e];
    }
    eoff[E_] = s; tpre[E_] = tt;
  }
}

__global__ __launch_bounds__(256) void scatter_k(const int* __restrict__ topi,
                                                 const float* __restrict__ topw,
                                                 int* __restrict__ cursor,
                                                 int* __restrict__ slots,
                                                 float* __restrict__ slotw) {
  int idx = blockIdx.x * 256 + threadIdx.x;
  if (idx >= T_ * TOPK_) return;
  int e = topi[idx];
  int pos = atomicAdd(&cursor[e], 1);
  slots[pos] = idx >> 2;
  slotw[pos] = topw[idx];
}

__global__ __launch_bounds__(256) void silumul_f_k(const float* __restrict__ g,
                                                   const float* __restrict__ u,
                                                   u16* __restrict__ a) {
  long long idx = ((long long)blockIdx.x * 256 + threadIdx.x) * 8;
  float4 g0 = *(const float4*)(g + idx);
  float4 g1 = *(const float4*)(g + idx + 4);
  float4 u0 = *(const float4*)(u + idx);
  float4 u1 = *(const float4*)(u + idx + 4);
  float gv[8] = {g0.x, g0.y, g0.z, g0.w, g1.x, g1.y, g1.z, g1.w};
  float uv[8] = {u0.x, u0.y, u0.z, u0.w, u1.x, u1.y, u1.z, u1.w};
  u16x8 o;
  #pragma unroll
  for (int q = 0; q < 8; ++q) {
    float x = gv[q];
    float sl = x / (1.f + __expf(-x));
    o[q] = f2b(sl * uv[q]);
  }
  *(u16x8*)(a + idx) = o;
}

__global__ __launch_bounds__(256) void sharedact_k(const u16* __restrict__ gu,
                                                   u16* __restrict__ act) {
  long long idx = ((long long)blockIdx.x * 256 + threadIdx.x) * 8;
  long long t = idx >> 10;
  int i = (int)(idx & 1023);
  const u16* row = gu + t * (2 * I_);
  u16x8 g = *(const u16x8*)(row + i);
  u16x8 u = *(const u16x8*)(row + I_ + i);
  u16x8 o;
  #pragma unroll
  for (int q = 0; q < 8; ++q) {
    float x = b2f(g[q]);
    float y = b2f(u[q]);
    float sl = x / (1.f + __expf(-x));
    o[q] = f2b(sl * y);
  }
  *(u16x8*)(act + t * I_ + i) = o;
}

// ---------------------------------------------------------------------------
extern "C" void kernel_launch(void* const* d_in, const int* in_sizes, int n_in,
                              void* d_out, int out_size, void* d_ws, size_t ws_size,
                              hipStream_t stream) {
  const float* x        = (const float*)d_in[0];
  const int* positions  = (const int*)d_in[1];
  const float* w_rms1   = (const float*)d_in[2];
  const float* w_rms2   = (const float*)d_in[3];
  const float* w_qkv    = (const float*)d_in[4];
  const float* w_o      = (const float*)d_in[5];
  const float* w_router = (const float*)d_in[6];
  const float* w1       = (const float*)d_in[7];
  const float* w3       = (const float*)d_in[8];
  const float* w2       = (const float*)d_in[9];
  const float* ws_gu    = (const float*)d_in[10];
  const float* ws_dn    = (const float*)d_in[11];
  float* out = (float*)d_out;

  char* ws = (char*)d_ws;
  size_t off = 0;
  auto alloc = [&](size_t bytes) {
    size_t o = off;
    off = (off + bytes + 255) & ~(size_t)255;
    return (void*)(ws + o);
  };
  u16*  h1b     = (u16*)alloc((size_t)T_ * H_ * 2);
  u16*  qkvb    = (u16*)alloc((size_t)T_ * QKVN_ * 2);
  u16*  q_r     = (u16*)alloc((size_t)NH_ * T_ * HD_ * 2);
  u16*  k_r     = (u16*)alloc((size_t)NKV_ * T_ * HD_ * 2);
  u16*  v_r     = (u16*)alloc((size_t)NKV_ * T_ * HD_ * 2);
  u16*  v_t     = (u16*)alloc((size_t)NKV_ * HD_ * T_ * 2);
  u16*  scoresP = (u16*)alloc((size_t)NH_ * T_ * T_ * 2);   // reused as g/u f32
  u16*  o_attn  = (u16*)alloc((size_t)T_ * H_ * 2);
  float* x1     = (float*)alloc((size_t)T_ * H_ * 4);
  float* h2f    = (float*)alloc((size_t)T_ * H_ * 4);
  u16*  h2b     = (u16*)alloc((size_t)T_ * H_ * 2);
  u16*  gub     = (u16*)alloc((size_t)T_ * 2 * I_ * 2);
  u16*  actsh   = (u16*)alloc((size_t)T_ * I_ * 2);
  float* logits = (float*)alloc((size_t)T_ * E_ * 4);
  int*  topi    = (int*)alloc((size_t)T_ * TOPK_ * 4);
  float* topw   = (float*)alloc((size_t)T_ * TOPK_ * 4);
  int*  cnt     = (int*)alloc(E_ * 4);
  int*  eoffp   = (int*)alloc((E_ + 1) * 4);
  int*  cursor  = (int*)alloc(E_ * 4);
  int*  tpre    = (int*)alloc((E_ + 1) * 4);
  int*  slots   = (int*)alloc((size_t)T_ * TOPK_ * 4);
  float* slotw  = (float*)alloc((size_t)T_ * TOPK_ * 4);
  u16*  a_g     = (u16*)alloc((size_t)T_ * TOPK_ * I_ * 2);

  float* g_f32 = (float*)scoresP;
  float* u_f32 = g_f32 + (size_t)T_ * TOPK_ * I_;

  hipMemsetAsync(cnt, 0, E_ * 4, stream);

  // 1. h = rmsnorm(x, w_rms1)
  rmsnorm_k<<<T_, 256, 0, stream>>>(x, w_rms1, h1b, nullptr);

  // 2. qkv = h @ w_qkv.T
  dense_gemm_k<float, 0, 0><<<dim3(24, 16, 1), 512, 0, stream>>>(
      h1b, w_qkv, qkvb, nullptr, nullptr, nullptr,
      H_, H_, H_, QKVN_, 1.f, 0, 0, 0, 1);

  // 3. RoPE + unpack; V transpose
  rope_k<<<T_, 256, 0, stream>>>(qkvb, positions, q_r, k_r, v_r);
  vtrans_k<<<dim3(16, 2, 4), 256, 0, stream>>>(v_r, v_t);

  // 4. scores = scale * q @ k^T per head (causal skip)
  dense_gemm_k<u16, 1, 1><<<dim3(8, 16, NH_), 512, 0, stream>>>(
      q_r, k_r, scoresP, nullptr, nullptr, nullptr,
      HD_, HD_, HD_, T_, SCALE_,
      (long long)T_ * HD_, (long long)T_ * HD_, (long long)T_ * T_, NH_ / NKV_);

  // 5. masked softmax rows
  softmax_k<<<NH_ * T_, 64, 0, stream>>>(scoresP);

  // 6. o = P @ V per head
  dense_gemm_k<u16, 0, 2><<<dim3(1, 16, NH_), 512, 0, stream>>>(
      scoresP, v_t, o_attn, nullptr, nullptr, nullptr,
      T_, T_, T_, H_, 1.f,
      (long long)T_ * T_, (long long)HD_ * T_, (long long)HD_, NH_ / NKV_);

  // 7. x1 = x + o @ w_o.T ; out = x1 (dual store, pre-init for atomics)
  dense_gemm_k<float, 5, 0><<<dim3(16, 16, 1), 512, 0, stream>>>(
      o_attn, w_o, nullptr, x1, out, x,
      H_, H_, H_, H_, 1.f, 0, 0, 0, 1);

  // 8. h2 = rmsnorm(x1, w_rms2)
  rmsnorm_k<<<T_, 256, 0, stream>>>(x1, w_rms2, h2b, h2f);

  // 9. router (block-per-token) + top-k + grouping
  router2_k<<<T_, 256, 0, stream>>>(h2f, w_router, logits);
  topk_k<<<4, 256, 0, stream>>>(logits, topi, topw);
  hist_k<<<16, 256, 0, stream>>>(topi, cnt);
  scan_k<<<1, 64, 0, stream>>>(cnt, eoffp, cursor, tpre);
  scatter_k<<<16, 256, 0, stream>>>(topi, topw, cursor, slots, slotw);

  // 10. FUSED up: MoE g/u (plain f32 stores) + shared-expert gu tail (bf16)
  moe_gemm_k<0, true><<<NMOE_ + 512, 512, 0, stream>>>(
      h2b, w1, w3, g_f32, u_f32,
      I_, H_, I_, H_, eoffp, tpre, slots, nullptr, (long long)H_ * I_,
      h2b, ws_gu, gub, nullptr);
  silumul_f_k<<<(T_ * TOPK_ * I_) / (256 * 8), 256, 0, stream>>>(g_f32, u_f32, a_g);
  sharedact_k<<<(T_ * I_) / (256 * 8), 256, 0, stream>>>(gub, actsh);

  // 11. FUSED down: MoE down atomics -> out + shared-down tail atomics -> out
  moe_gemm_k<1, false><<<NMOE_ + 512, 512, 0, stream>>>(
      a_g, w2, nullptr, out, nullptr,
      H_, I_, H_, I_, eoffp, tpre, slots, slotw, (long long)I_ * H_,
      actsh, ws_dn, nullptr, out);
}

// Round 16
// 585.560 us; speedup vs baseline: 1.2383x; 1.2383x over previous
//
#include <hip/hip_runtime.h>
#include <hip/hip_bf16.h>
#include <math.h>
#include <stdint.h>

#define T_ 1024
#define H_ 2048
#define NH_ 16
#define NKV_ 4
#define HD_ 128
#define E_ 32
#define TOPK_ 4
#define I_ 1024
#define QKVN_ 3072
#define EPS_ 1e-6f
#define THETA_ 600000.0f
#define SCALE_ 0.08838834764831845f

typedef unsigned short u16;
typedef u16 u16x4 __attribute__((ext_vector_type(4)));
typedef u16 u16x8 __attribute__((ext_vector_type(8)));
typedef __bf16 bf16x8 __attribute__((ext_vector_type(8)));
typedef float f32x4 __attribute__((ext_vector_type(4)));

__device__ __forceinline__ u16 f2b(float f) {
  unsigned u = __builtin_bit_cast(unsigned, f);
  u += 0x7FFFu + ((u >> 16) & 1u);
  return (u16)(u >> 16);
}
__device__ __forceinline__ float b2f(u16 x) {
  unsigned u = ((unsigned)x) << 16;
  return __builtin_bit_cast(float, u);
}
__device__ __forceinline__ int s2(int i) { return (i ^ (i >> 2)) & 3; }
__device__ __forceinline__ int sw3(int i) { return (i ^ (i >> 3)) & 7; }

__device__ __forceinline__ void gload16(const void* g, void* l) {
  __builtin_amdgcn_global_load_lds(
      reinterpret_cast<const __attribute__((address_space(1))) unsigned int*>(
          reinterpret_cast<uintptr_t>(g)),
      reinterpret_cast<__attribute__((address_space(3))) unsigned int*>(
          reinterpret_cast<uintptr_t>(l)),
      16, 0, 0);
}

// ---------------------------------------------------------------------------
// MoE grouped GEMM (R14, measured best): M64 x N64 x BK64, 512 threads
// (8 waves, 2m x 4n of 16), 2-buffer LDS (32 KB) -> 4 blocks/CU.
// COMPACT STATIC grid: 3072 blocks; idx -> (t = idx>>5 tile, xx = idx&31);
// real tiles contiguous via tpre prefix; empties only at the tail.
// A: bf16 [64][64] via gload16 (all 8 waves, 1 inst/thread), sw3 chunk swizzle.
// B: f32 [k][n] reg-staged (8 dwords/thread), converted once, stored
// transposed [n][64k] with sw3 chunk swizzle.
// EPI 0: fused up (xx<16 -> w1/O1, else w3/O2), plain store at slot row.
// EPI 1: down, atomicAdd slotw*acc into O1[token].
// ---------------------------------------------------------------------------
template<int EPI, bool GATHER>
__global__ __launch_bounds__(512, 8) void moe_gemm_k(
    const u16* __restrict__ A, const float* __restrict__ B, const float* __restrict__ B2,
    float* __restrict__ O1, float* __restrict__ O2,
    int NW, int lda, int ldb, int K,
    const int* __restrict__ eoff, const int* __restrict__ tpre,
    const int* __restrict__ slots, const float* __restrict__ slotw, long long sBz)
{
  __shared__ u16 As[2][64 * 64];   // 8 KB per buffer
  __shared__ u16 Bs[2][64 * 64];   // 8 KB per buffer

  const int idx = blockIdx.x;
  const int t = idx >> 5;
  const int xx = idx & 31;
  if (t >= tpre[E_]) return;
  int lo = 0, hi = E_;
  while (hi - lo > 1) { int mid = (lo + hi) >> 1; if (tpre[mid] <= t) lo = mid; else hi = mid; }
  const int e = lo;
  const int mb = t - tpre[e];
  const int goff = eoff[e];
  const int Mloc = eoff[e + 1] - goff;
  const int m0 = mb * 64;

  const float* Bp;
  float* Op;
  int n0;
  if constexpr (EPI == 0) {
    int wsel = xx >> 4;
    n0 = (xx & 15) * 64;
    Bp = (wsel ? B2 : B) + (long long)e * sBz;
    Op = wsel ? O2 : O1;
  } else {
    n0 = xx * 64;
    Bp = B + (long long)e * sBz;
    Op = O1;
  }
  const u16* Ae = GATHER ? A : (A + (long long)goff * lda);

  const int tid = threadIdx.x;
  const int lane = tid & 63;
  const int wv = tid >> 6;
  const int wm = wv >> 2, wn = wv & 3;
  const int kg = lane >> 4;
  const int cr = lane & 15;

  const u16* Abase;
  {
    int r = wv * 8 + (lane >> 3);
    int rr = m0 + r;
    if (rr > Mloc - 1) rr = Mloc - 1;
    long long grow = GATHER ? (long long)slots[goff + rr] : (long long)rr;
    Abase = Ae + grow * (long long)lda + (((lane & 7) ^ sw3(r)) << 3);
  }
  auto stageA = [&](int bf, int k0) {
    gload16(Abase + k0, &As[bf][wv * 512]);
  };

  const int bn = tid & 63;
  const int kc = tid >> 6;
  const float* Bbase = Bp + (long long)(kc << 3) * ldb + n0 + bn;
  const int bws = bn * 64 + ((kc ^ sw3(bn)) << 3);

  float br[8];
  auto loadB = [&](int k0) {
    const float* p = Bbase + (long long)k0 * ldb;
    #pragma unroll
    for (int j = 0; j < 8; ++j) br[j] = p[(long long)j * ldb];
  };
  auto writeB = [&](int bf) {
    u16x8 o;
    #pragma unroll
    for (int j = 0; j < 8; ++j) o[j] = f2b(br[j]);
    *(u16x8*)(&Bs[bf][bws]) = o;
  };

  f32x4 acc[2];
  acc[0] = f32x4{0.f, 0.f, 0.f, 0.f};
  acc[1] = f32x4{0.f, 0.f, 0.f, 0.f};

  int aoff[2], asw[2];
  #pragma unroll
  for (int m = 0; m < 2; ++m) {
    int r = wm * 32 + m * 16 + cr;
    aoff[m] = r * 64; asw[m] = sw3(r);
  }
  const int bc = wn * 16 + cr;
  const int boff = bc * 64;
  const int bsw = sw3(bc);

  auto mfma_step = [&](int bf) {
    const u16* Ap = &As[bf][0];
    const u16* Bq = &Bs[bf][0];
    #pragma unroll
    for (int sub = 0; sub < 2; ++sub) {
      int ck = kg + sub * 4;
      bf16x8 af0 = __builtin_bit_cast(bf16x8, *(const u16x8*)(Ap + aoff[0] + ((ck ^ asw[0]) << 3)));
      bf16x8 af1 = __builtin_bit_cast(bf16x8, *(const u16x8*)(Ap + aoff[1] + ((ck ^ asw[1]) << 3)));
      bf16x8 bfr = __builtin_bit_cast(bf16x8, *(const u16x8*)(Bq + boff + ((ck ^ bsw) << 3)));
      acc[0] = __builtin_amdgcn_mfma_f32_16x16x32_bf16(af0, bfr, acc[0], 0, 0, 0);
      acc[1] = __builtin_amdgcn_mfma_f32_16x16x32_bf16(af1, bfr, acc[1], 0, 0, 0);
    }
  };

  loadB(0);
  stageA(0, 0);
  writeB(0);
  __syncthreads();

  int buf = 0;
  for (int ks = 0; ks < K; ks += 64) {
    bool more = (ks + 64) < K;
    if (more) { loadB(ks + 64); stageA(buf ^ 1, ks + 64); }
    mfma_step(buf);
    if (more) writeB(buf ^ 1);
    __syncthreads();
    buf ^= 1;
  }

  const int rq = lane >> 4;
  #pragma unroll
  for (int m = 0; m < 2; ++m) {
    #pragma unroll
    for (int j = 0; j < 4; ++j) {
      int row = m0 + wm * 32 + m * 16 + rq * 4 + j;
      if (row >= Mloc) continue;
      int col = n0 + wn * 16 + cr;
      if constexpr (EPI == 0) {
        Op[(long long)(goff + row) * NW + col] = acc[m][j];
      } else {
        int tok = slots[goff + row];
        float wgt = slotw[goff + row];
        atomicAdd(Op + (long long)tok * NW + col, wgt * acc[m][j]);
      }
    }
  }
}

// ---------------------------------------------------------------------------
// Dense GEMM (R14): M64 x N128 x BK32, 512 threads.
// ---------------------------------------------------------------------------
template<typename TB, int EPI, int CAUSAL>
__global__ __launch_bounds__(512, 8) void dense_gemm_k(
    const u16* __restrict__ A, const TB* __restrict__ B,
    u16* __restrict__ Cb, float* __restrict__ Cf,
    const float* __restrict__ res1, const float* __restrict__ res2,
    int K, int lda, int ldb, int ldc, float alpha,
    long long sAz, long long sBz, long long sCz, int bdivz)
{
  __shared__ u16 As[2][64 * 32];
  __shared__ u16 Bs[2][128 * 32];

  const int m0 = blockIdx.y * 64;
  const int n0 = blockIdx.x * 128;
  if (CAUSAL == 1 && n0 > m0 + 63) return;
  const long long z = blockIdx.z;
  const u16* Ae = A + z * sAz;
  const TB* Be = B + (long long)(z / bdivz) * sBz;
  u16* Cwb = Cb ? Cb + z * sCz : nullptr;

  int kend = K;
  if (CAUSAL == 2) { int ke = m0 + 64; if (ke < kend) kend = ke; }

  const int tid = threadIdx.x;
  const int lane = tid & 63;
  const int wv = tid >> 6;
  const int wm = wv >> 2, wn = wv & 3;

  const u16* Abase = nullptr;
  if (wv < 4) {
    int r = wv * 16 + (lane >> 2);
    Abase = Ae + (long long)(m0 + r) * lda + (((lane & 3) ^ s2(r)) << 3);
  }
  auto stageA = [&](int bf, int k0) {
    if (wv < 4) gload16(Abase + k0, &As[bf][wv * 512]);
  };

  const u16* Bu16base = nullptr;
  const float* Bf32base = nullptr;
  int bws = 0;
  if constexpr (sizeof(TB) == 2) {
    int r = wv * 16 + (lane >> 2);
    Bu16base = (const u16*)Be + (long long)(n0 + r) * ldb + (((lane & 3) ^ s2(r)) << 3);
  } else {
    int bn = tid >> 2, bkq = tid & 3;
    Bf32base = (const float*)Be + (long long)(n0 + bn) * ldb + (bkq << 3);
    bws = bn * 32 + ((bkq ^ s2(bn)) << 3);
  }
  float br[8];
  auto loadB = [&](int k0) {
    const float* p = Bf32base + k0;
    float4 a = *(const float4*)p;
    float4 b = *(const float4*)(p + 4);
    br[0] = a.x; br[1] = a.y; br[2] = a.z; br[3] = a.w;
    br[4] = b.x; br[5] = b.y; br[6] = b.z; br[7] = b.w;
  };
  auto writeB = [&](int bf) {
    u16x8 o;
    #pragma unroll
    for (int j = 0; j < 8; ++j) o[j] = f2b(br[j]);
    *(u16x8*)(&Bs[bf][bws]) = o;
  };
  auto stageBu = [&](int bf, int k0) {
    gload16(Bu16base + k0, &Bs[bf][wv * 512]);
  };

  f32x4 acc[2][2];
  #pragma unroll
  for (int m = 0; m < 2; ++m)
    #pragma unroll
    for (int n = 0; n < 2; ++n)
      acc[m][n] = f32x4{0.f, 0.f, 0.f, 0.f};

  const int kg = lane >> 4;
  const int cr = lane & 15;

  int aoff[2], boff[2];
  #pragma unroll
  for (int m = 0; m < 2; ++m) {
    int r = wm * 32 + m * 16 + cr;
    aoff[m] = r * 32 + ((kg ^ s2(r)) << 3);
  }
  #pragma unroll
  for (int n = 0; n < 2; ++n) {
    int c = wn * 32 + n * 16 + cr;
    boff[n] = c * 32 + ((kg ^ s2(c)) << 3);
  }

  if constexpr (sizeof(TB) == 4) {
    loadB(0); stageA(0, 0); writeB(0);
  } else {
    stageA(0, 0); stageBu(0, 0);
  }
  __syncthreads();

  int buf = 0;
  for (int ks = 0; ks < kend; ks += 32) {
    bool more = (ks + 32) < kend;
    if (more) {
      if constexpr (sizeof(TB) == 4) { loadB(ks + 32); stageA(buf ^ 1, ks + 32); }
      else { stageA(buf ^ 1, ks + 32); stageBu(buf ^ 1, ks + 32); }
    }
    const u16* Ap = &As[buf][0];
    const u16* Bq = &Bs[buf][0];
    bf16x8 af[2], bfr[2];
    #pragma unroll
    for (int m = 0; m < 2; ++m)
      af[m] = __builtin_bit_cast(bf16x8, *(const u16x8*)(Ap + aoff[m]));
    #pragma unroll
    for (int n = 0; n < 2; ++n)
      bfr[n] = __builtin_bit_cast(bf16x8, *(const u16x8*)(Bq + boff[n]));
    #pragma unroll
    for (int m = 0; m < 2; ++m)
      #pragma unroll
      for (int n = 0; n < 2; ++n)
        acc[m][n] = __builtin_amdgcn_mfma_f32_16x16x32_bf16(af[m], bfr[n], acc[m][n], 0, 0, 0);
    if constexpr (sizeof(TB) == 4) { if (more) writeB(buf ^ 1); }
    __syncthreads();
    buf ^= 1;
  }

  const int rq = lane >> 4;
  #pragma unroll
  for (int m = 0; m < 2; ++m) {
    #pragma unroll
    for (int j = 0; j < 4; ++j) {
      int row = m0 + wm * 32 + m * 16 + rq * 4 + j;
      #pragma unroll
      for (int n = 0; n < 2; ++n) {
        int col = n0 + wn * 32 + n * 16 + cr;
        float v = acc[m][n][j];
        long long o = (long long)row * ldc + col;
        if constexpr (EPI == 0) {
          Cwb[o] = f2b(v);
        } else if constexpr (EPI == 1) {
          Cwb[o] = f2b(v * alpha);
        } else if constexpr (EPI == 2) {
          Cf[o] = res1[o] + v;
        } else {
          Cf[o] = res1[o] + res2[o] + v;
        }
      }
    }
  }
}

// ---------------------------------------------------------------------------
__global__ __launch_bounds__(256) void vtrans_k(const u16* __restrict__ v_r,
                                                u16* __restrict__ v_t) {
  __shared__ u16 t[64][72];
  int kv = blockIdx.z;
  int s0 = blockIdx.x * 64, d0 = blockIdx.y * 64;
  int tid = threadIdx.x;
  int sr = tid >> 2, dq = (tid & 3) * 16;
  const u16* src = v_r + ((long long)kv * T_ + s0 + sr) * HD_ + d0 + dq;
  *(u16x8*)&t[sr][dq] = *(const u16x8*)src;
  *(u16x8*)&t[sr][dq + 8] = *(const u16x8*)(src + 8);
  __syncthreads();
  int dr = tid >> 2, sq = (tid & 3) * 16;
  u16* dst = v_t + ((long long)kv * HD_ + d0 + dr) * T_ + s0 + sq;
  u16x8 o0, o1;
  #pragma unroll
  for (int j = 0; j < 8; ++j) { o0[j] = t[sq + j][dr]; o1[j] = t[sq + 8 + j][dr]; }
  *(u16x8*)dst = o0;
  *(u16x8*)(dst + 8) = o1;
}

// ---------------------------------------------------------------------------
__global__ __launch_bounds__(256) void rmsnorm_k(const float* __restrict__ x,
                                                 const float* __restrict__ w,
                                                 u16* __restrict__ outb,
                                                 float* __restrict__ outf) {
  int t = blockIdx.x;
  int tid = threadIdx.x;
  const float* xr = x + (long long)t * H_;
  float4 a = *(const float4*)(xr + tid * 8);
  float4 b = *(const float4*)(xr + tid * 8 + 4);
  float ss = a.x * a.x + a.y * a.y + a.z * a.z + a.w * a.w +
             b.x * b.x + b.y * b.y + b.z * b.z + b.w * b.w;
  #pragma unroll
  for (int o = 32; o; o >>= 1) ss += __shfl_down(ss, o);
  __shared__ float red[4];
  if ((tid & 63) == 0) red[tid >> 6] = ss;
  __syncthreads();
  float sc = rsqrtf((red[0] + red[1] + red[2] + red[3]) * (1.0f / H_) + EPS_);
  float vo[8] = {a.x, a.y, a.z, a.w, b.x, b.y, b.z, b.w};
  const float* wr = w + tid * 8;
  u16x8 ob;
  #pragma unroll
  for (int q = 0; q < 8; ++q) {
    float val = vo[q] * sc * wr[q];
    ob[q] = f2b(val);
    if (outf) outf[(long long)t * H_ + tid * 8 + q] = val;
  }
  *(u16x8*)(outb + (long long)t * H_ + tid * 8) = ob;
}

__global__ __launch_bounds__(256) void rope_k(const u16* __restrict__ qkv,
                                              const int* __restrict__ pos,
                                              u16* __restrict__ q_r,
                                              u16* __restrict__ k_r,
                                              u16* __restrict__ v_r) {
  int t = blockIdx.x;
  int tid = threadIdx.x;
  float p = (float)pos[t];
  const u16* row = qkv + (long long)t * QKVN_;
  const float cfac = logf(THETA_) * (1.0f / 64.0f);
  #pragma unroll
  for (int it = 0; it < 4; ++it) {
    int item = it * 256 + tid;
    int h = item >> 6, d = item & 63;
    float inv = expf(-cfac * (float)d);
    float ang = p * inv;
    float c = cosf(ang), s = sinf(ang);
    float x1v = b2f(row[h * 128 + d]);
    float x2v = b2f(row[h * 128 + 64 + d]);
    u16* dst = q_r + ((long long)h * T_ + t) * HD_;
    dst[d] = f2b(x1v * c - x2v * s);
    dst[d + 64] = f2b(x1v * s + x2v * c);
  }
  {
    int item = tid;
    int kv = item >> 6, d = item & 63;
    float inv = expf(-cfac * (float)d);
    float ang = p * inv;
    float c = cosf(ang), s = sinf(ang);
    float x1v = b2f(row[NH_ * HD_ + kv * 128 + d]);
    float x2v = b2f(row[NH_ * HD_ + kv * 128 + 64 + d]);
    u16* dst = k_r + ((long long)kv * T_ + t) * HD_;
    dst[d] = f2b(x1v * c - x2v * s);
    dst[d + 64] = f2b(x1v * s + x2v * c);
  }
  #pragma unroll
  for (int it = 0; it < 2; ++it) {
    int item = it * 256 + tid;
    int kv = item >> 7, d = item & 127;
    v_r[((long long)kv * T_ + t) * HD_ + d] = row[(NH_ + NKV_) * HD_ + kv * 128 + d];
  }
}

__global__ __launch_bounds__(64) void softmax_k(u16* __restrict__ P) {
  int r = blockIdx.x;
  int h = r >> 10, i = r & 1023;
  u16* row = P + ((long long)h * T_ + i) * T_;
  int lane = threadIdx.x;
  int n = i + 1;
  float vals[16];
  float mx = -1e30f;
  #pragma unroll
  for (int it = 0; it < 16; ++it) {
    int j = it * 64 + lane;
    float s = (j < n) ? b2f(row[j]) : -1e30f;
    vals[it] = s;
    mx = fmaxf(mx, s);
  }
  #pragma unroll
  for (int o = 32; o; o >>= 1) mx = fmaxf(mx, __shfl_xor(mx, o));
  float sum = 0.f;
  #pragma unroll
  for (int it = 0; it < 16; ++it) {
    int j = it * 64 + lane;
    float e = (j < n) ? __expf(vals[it] - mx) : 0.f;
    vals[it] = e;
    sum += e;
  }
  #pragma unroll
  for (int o = 32; o; o >>= 1) sum += __shfl_xor(sum, o);
  float inv = 1.f / sum;
  #pragma unroll
  for (int it = 0; it < 16; ++it) {
    int j = it * 64 + lane;
    row[j] = f2b(vals[it] * inv);
  }
}

__global__ __launch_bounds__(256) void router2_k(const float* __restrict__ h2,
                                                 const float* __restrict__ wr,
                                                 float* __restrict__ logits) {
  __shared__ float hrow[H_];
  int t = blockIdx.x;
  int tid = threadIdx.x;
  float4 a = *(const float4*)(h2 + (long long)t * H_ + tid * 8);
  float4 b = *(const float4*)(h2 + (long long)t * H_ + tid * 8 + 4);
  *(float4*)&hrow[tid * 8] = a;
  *(float4*)&hrow[tid * 8 + 4] = b;
  __syncthreads();
  int wv = tid >> 6, lane = tid & 63;
  #pragma unroll
  for (int ei = 0; ei < 8; ++ei) {
    int e = wv * 8 + ei;
    const float* wrow = wr + (long long)e * H_;
    float s = 0.f;
    #pragma unroll
    for (int it = 0; it < 8; ++it) {
      int k = it * 256 + lane * 4;
      float4 w4 = *(const float4*)(wrow + k);
      s += hrow[k] * w4.x + hrow[k + 1] * w4.y + hrow[k + 2] * w4.z + hrow[k + 3] * w4.w;
    }
    #pragma unroll
    for (int o = 32; o; o >>= 1) s += __shfl_xor(s, o);
    if (lane == 0) logits[t * E_ + e] = s;
  }
}

__global__ __launch_bounds__(256) void topk_k(const float* __restrict__ logits,
                                              int* __restrict__ topi,
                                              float* __restrict__ topw) {
  int t = blockIdx.x * 256 + threadIdx.x;
  if (t >= T_) return;
  float l[E_];
  #pragma unroll
  for (int e = 0; e < E_; ++e) l[e] = logits[t * E_ + e];
  int sel[TOPK_];
  float sv[TOPK_];
  unsigned used = 0;
  for (int j = 0; j < TOPK_; ++j) {
    float best = -1e30f;
    int bi = 0;
    for (int e = 0; e < E_; ++e) {
      if (used & (1u << e)) continue;
      if (l[e] > best) { best = l[e]; bi = e; }
    }
    used |= 1u << bi;
    sel[j] = bi;
    sv[j] = best;
  }
  float mx = sv[0];
  float s = 0.f;
  #pragma unroll
  for (int j = 0; j < TOPK_; ++j) { sv[j] = __expf(sv[j] - mx); s += sv[j]; }
  float inv = 1.f / s;
  #pragma unroll
  for (int j = 0; j < TOPK_; ++j) {
    topi[t * TOPK_ + j] = sel[j];
    topw[t * TOPK_ + j] = sv[j] * inv;
  }
}

__global__ __launch_bounds__(256) void hist_k(const int* __restrict__ topi, int* __restrict__ cnt) {
  int idx = blockIdx.x * 256 + threadIdx.x;
  if (idx < T_ * TOPK_) atomicAdd(&cnt[topi[idx]], 1);
}

__global__ __launch_bounds__(64) void scan_k(const int* __restrict__ cnt,
                                             int* __restrict__ eoff,
                                             int* __restrict__ cursor,
                                             int* __restrict__ tpre) {
  if (threadIdx.x == 0) {
    int s = 0, tt = 0;
    for (int e = 0; e < E_; ++e) {
      eoff[e] = s; cursor[e] = s; tpre[e] = tt;
      tt += (cnt[e] + 63) >> 6;
      s += cnt[e];
    }
    eoff[E_] = s; tpre[E_] = tt;
  }
}

__global__ __launch_bounds__(256) void scatter_k(const int* __restrict__ topi,
                                                 const float* __restrict__ topw,
                                                 int* __restrict__ cursor,
                                                 int* __restrict__ slots,
                                                 float* __restrict__ slotw) {
  int idx = blockIdx.x * 256 + threadIdx.x;
  if (idx >= T_ * TOPK_) return;
  int e = topi[idx];
  int pos = atomicAdd(&cursor[e], 1);
  slots[pos] = idx >> 2;
  slotw[pos] = topw[idx];
}

__global__ __launch_bounds__(256) void silumul_f_k(const float* __restrict__ g,
                                                   const float* __restrict__ u,
                                                   u16* __restrict__ a) {
  long long idx = ((long long)blockIdx.x * 256 + threadIdx.x) * 8;
  float4 g0 = *(const float4*)(g + idx);
  float4 g1 = *(const float4*)(g + idx + 4);
  float4 u0 = *(const float4*)(u + idx);
  float4 u1 = *(const float4*)(u + idx + 4);
  float gv[8] = {g0.x, g0.y, g0.z, g0.w, g1.x, g1.y, g1.z, g1.w};
  float uv[8] = {u0.x, u0.y, u0.z, u0.w, u1.x, u1.y, u1.z, u1.w};
  u16x8 o;
  #pragma unroll
  for (int q = 0; q < 8; ++q) {
    float x = gv[q];
    float sl = x / (1.f + __expf(-x));
    o[q] = f2b(sl * uv[q]);
  }
  *(u16x8*)(a + idx) = o;
}

__global__ __launch_bounds__(256) void sharedact_k(const u16* __restrict__ gu,
                                                   u16* __restrict__ act) {
  long long idx = ((long long)blockIdx.x * 256 + threadIdx.x) * 8;
  long long t = idx >> 10;
  int i = (int)(idx & 1023);
  const u16* row = gu + t * (2 * I_);
  u16x8 g = *(const u16x8*)(row + i);
  u16x8 u = *(const u16x8*)(row + I_ + i);
  u16x8 o;
  #pragma unroll
  for (int q = 0; q < 8; ++q) {
    float x = b2f(g[q]);
    float y = b2f(u[q]);
    float sl = x / (1.f + __expf(-x));
    o[q] = f2b(sl * y);
  }
  *(u16x8*)(act + t * I_ + i) = o;
}

// ---------------------------------------------------------------------------
extern "C" void kernel_launch(void* const* d_in, const int* in_sizes, int n_in,
                              void* d_out, int out_size, void* d_ws, size_t ws_size,
                              hipStream_t stream) {
  const float* x        = (const float*)d_in[0];
  const int* positions  = (const int*)d_in[1];
  const float* w_rms1   = (const float*)d_in[2];
  const float* w_rms2   = (const float*)d_in[3];
  const float* w_qkv    = (const float*)d_in[4];
  const float* w_o      = (const float*)d_in[5];
  const float* w_router = (const float*)d_in[6];
  const float* w1       = (const float*)d_in[7];
  const float* w3       = (const float*)d_in[8];
  const float* w2       = (const float*)d_in[9];
  const float* ws_gu    = (const float*)d_in[10];
  const float* ws_dn    = (const float*)d_in[11];
  float* out = (float*)d_out;

  char* ws = (char*)d_ws;
  size_t off = 0;
  auto alloc = [&](size_t bytes) {
    size_t o = off;
    off = (off + bytes + 255) & ~(size_t)255;
    return (void*)(ws + o);
  };
  u16*  h1b     = (u16*)alloc((size_t)T_ * H_ * 2);
  u16*  qkvb    = (u16*)alloc((size_t)T_ * QKVN_ * 2);
  u16*  q_r     = (u16*)alloc((size_t)NH_ * T_ * HD_ * 2);
  u16*  k_r     = (u16*)alloc((size_t)NKV_ * T_ * HD_ * 2);
  u16*  v_r     = (u16*)alloc((size_t)NKV_ * T_ * HD_ * 2);
  u16*  v_t     = (u16*)alloc((size_t)NKV_ * HD_ * T_ * 2);
  u16*  scoresP = (u16*)alloc((size_t)NH_ * T_ * T_ * 2);   // reused as g/u f32
  u16*  o_attn  = (u16*)alloc((size_t)T_ * H_ * 2);
  float* x1     = (float*)alloc((size_t)T_ * H_ * 4);
  float* h2f    = (float*)alloc((size_t)T_ * H_ * 4);
  u16*  h2b     = (u16*)alloc((size_t)T_ * H_ * 2);
  u16*  gub     = (u16*)alloc((size_t)T_ * 2 * I_ * 2);
  u16*  actsh   = (u16*)alloc((size_t)T_ * I_ * 2);
  float* logits = (float*)alloc((size_t)T_ * E_ * 4);
  int*  topi    = (int*)alloc((size_t)T_ * TOPK_ * 4);
  float* topw   = (float*)alloc((size_t)T_ * TOPK_ * 4);
  int*  cnt     = (int*)alloc(E_ * 4);
  int*  eoffp   = (int*)alloc((E_ + 1) * 4);
  int*  cursor  = (int*)alloc(E_ * 4);
  int*  tpre    = (int*)alloc((E_ + 1) * 4);
  int*  slots   = (int*)alloc((size_t)T_ * TOPK_ * 4);
  float* slotw  = (float*)alloc((size_t)T_ * TOPK_ * 4);
  u16*  a_g     = (u16*)alloc((size_t)T_ * TOPK_ * I_ * 2);
  float* routed = (float*)alloc((size_t)T_ * H_ * 4);

  float* g_f32 = (float*)scoresP;
  float* u_f32 = g_f32 + (size_t)T_ * TOPK_ * I_;

  hipMemsetAsync(routed, 0, (size_t)T_ * H_ * 4, stream);
  hipMemsetAsync(cnt, 0, E_ * 4, stream);

  // 1. h = rmsnorm(x, w_rms1)
  rmsnorm_k<<<T_, 256, 0, stream>>>(x, w_rms1, h1b, nullptr);

  // 2. qkv = h @ w_qkv.T
  dense_gemm_k<float, 0, 0><<<dim3(24, 16, 1), 512, 0, stream>>>(
      h1b, w_qkv, qkvb, nullptr, nullptr, nullptr,
      H_, H_, H_, QKVN_, 1.f, 0, 0, 0, 1);

  // 3. RoPE + unpack; V transpose
  rope_k<<<T_, 256, 0, stream>>>(qkvb, positions, q_r, k_r, v_r);
  vtrans_k<<<dim3(16, 2, 4), 256, 0, stream>>>(v_r, v_t);

  // 4. scores = scale * q @ k^T per head (causal skip)
  dense_gemm_k<u16, 1, 1><<<dim3(8, 16, NH_), 512, 0, stream>>>(
      q_r, k_r, scoresP, nullptr, nullptr, nullptr,
      HD_, HD_, HD_, T_, SCALE_,
      (long long)T_ * HD_, (long long)T_ * HD_, (long long)T_ * T_, NH_ / NKV_);

  // 5. masked softmax rows
  softmax_k<<<NH_ * T_, 64, 0, stream>>>(scoresP);

  // 6. o = P @ V per head
  dense_gemm_k<u16, 0, 2><<<dim3(1, 16, NH_), 512, 0, stream>>>(
      scoresP, v_t, o_attn, nullptr, nullptr, nullptr,
      T_, T_, T_, H_, 1.f,
      (long long)T_ * T_, (long long)HD_ * T_, (long long)HD_, NH_ / NKV_);

  // 7. x1 = x + o @ w_o.T
  dense_gemm_k<float, 2, 0><<<dim3(16, 16, 1), 512, 0, stream>>>(
      o_attn, w_o, nullptr, x1, x, nullptr,
      H_, H_, H_, H_, 1.f, 0, 0, 0, 1);

  // 8. h2 = rmsnorm(x1, w_rms2)
  rmsnorm_k<<<T_, 256, 0, stream>>>(x1, w_rms2, h2b, h2f);

  // 9. router (block-per-token) + top-k + grouping
  router2_k<<<T_, 256, 0, stream>>>(h2f, w_router, logits);
  topk_k<<<4, 256, 0, stream>>>(logits, topi, topw);
  hist_k<<<16, 256, 0, stream>>>(topi, cnt);
  scan_k<<<1, 64, 0, stream>>>(cnt, eoffp, cursor, tpre);
  scatter_k<<<16, 256, 0, stream>>>(topi, topw, cursor, slots, slotw);

  // 10. fused grouped up (compact static grid, N64 x BK64, plain stores)
  moe_gemm_k<0, true><<<3072, 512, 0, stream>>>(
      h2b, w1, w3, g_f32, u_f32,
      I_, H_, I_, H_, eoffp, tpre, slots, nullptr, (long long)H_ * I_);
  silumul_f_k<<<(T_ * TOPK_ * I_) / (256 * 8), 256, 0, stream>>>(g_f32, u_f32, a_g);

  // 11. grouped down (compact static grid, N64 x BK64)
  moe_gemm_k<1, false><<<3072, 512, 0, stream>>>(
      a_g, w2, nullptr, routed, nullptr,
      H_, I_, H_, I_, eoffp, tpre, slots, slotw, (long long)I_ * H_);

  // 12. shared expert
  dense_gemm_k<float, 0, 0><<<dim3(16, 16, 1), 512, 0, stream>>>(
      h2b, ws_gu, gub, nullptr, nullptr, nullptr,
      H_, H_, H_, 2 * I_, 1.f, 0, 0, 0, 1);
  sharedact_k<<<(T_ * I_) / (256 * 8), 256, 0, stream>>>(gub, actsh);

  // 13. out = f32(x1 + routed + act @ ws_down.T)
  dense_gemm_k<float, 4, 0><<<dim3(16, 16, 1), 512, 0, stream>>>(
      actsh, ws_dn, nullptr, out, x1, routed,
      I_, I_, I_, H_, 1.f, 0, 0, 0, 1);
}

// Round 17
// 580.902 us; speedup vs baseline: 1.2483x; 1.0080x over previous
//
#include <hip/hip_runtime.h>
#include <hip/hip_bf16.h>
#include <math.h>
#include <stdint.h>

#define T_ 1024
#define H_ 2048
#define NH_ 16
#define NKV_ 4
#define HD_ 128
#define E_ 32
#define TOPK_ 4
#define I_ 1024
#define QKVN_ 3072
#define EPS_ 1e-6f
#define THETA_ 600000.0f
#define SCALE_ 0.08838834764831845f

typedef unsigned short u16;
typedef u16 u16x4 __attribute__((ext_vector_type(4)));
typedef u16 u16x8 __attribute__((ext_vector_type(8)));
typedef __bf16 bf16x8 __attribute__((ext_vector_type(8)));
typedef float f32x4 __attribute__((ext_vector_type(4)));

__device__ __forceinline__ u16 f2b(float f) {
  unsigned u = __builtin_bit_cast(unsigned, f);
  u += 0x7FFFu + ((u >> 16) & 1u);
  return (u16)(u >> 16);
}
__device__ __forceinline__ float b2f(u16 x) {
  unsigned u = ((unsigned)x) << 16;
  return __builtin_bit_cast(float, u);
}
__device__ __forceinline__ int s2(int i) { return (i ^ (i >> 2)) & 3; }
__device__ __forceinline__ int sw3(int i) { return (i ^ (i >> 3)) & 7; }

__device__ __forceinline__ void gload16(const void* g, void* l) {
  __builtin_amdgcn_global_load_lds(
      reinterpret_cast<const __attribute__((address_space(1))) unsigned int*>(
          reinterpret_cast<uintptr_t>(g)),
      reinterpret_cast<__attribute__((address_space(3))) unsigned int*>(
          reinterpret_cast<uintptr_t>(l)),
      16, 0, 0);
}

// ---------------------------------------------------------------------------
// MoE grouped GEMM (R14/R16, measured best — UNCHANGED): M64 x N64 x BK64.
// ---------------------------------------------------------------------------
template<int EPI, bool GATHER>
__global__ __launch_bounds__(512, 8) void moe_gemm_k(
    const u16* __restrict__ A, const float* __restrict__ B, const float* __restrict__ B2,
    float* __restrict__ O1, float* __restrict__ O2,
    int NW, int lda, int ldb, int K,
    const int* __restrict__ eoff, const int* __restrict__ tpre,
    const int* __restrict__ slots, const float* __restrict__ slotw, long long sBz)
{
  __shared__ u16 As[2][64 * 64];
  __shared__ u16 Bs[2][64 * 64];

  const int idx = blockIdx.x;
  const int t = idx >> 5;
  const int xx = idx & 31;
  if (t >= tpre[E_]) return;
  int lo = 0, hi = E_;
  while (hi - lo > 1) { int mid = (lo + hi) >> 1; if (tpre[mid] <= t) lo = mid; else hi = mid; }
  const int e = lo;
  const int mb = t - tpre[e];
  const int goff = eoff[e];
  const int Mloc = eoff[e + 1] - goff;
  const int m0 = mb * 64;

  const float* Bp;
  float* Op;
  int n0;
  if constexpr (EPI == 0) {
    int wsel = xx >> 4;
    n0 = (xx & 15) * 64;
    Bp = (wsel ? B2 : B) + (long long)e * sBz;
    Op = wsel ? O2 : O1;
  } else {
    n0 = xx * 64;
    Bp = B + (long long)e * sBz;
    Op = O1;
  }
  const u16* Ae = GATHER ? A : (A + (long long)goff * lda);

  const int tid = threadIdx.x;
  const int lane = tid & 63;
  const int wv = tid >> 6;
  const int wm = wv >> 2, wn = wv & 3;
  const int kg = lane >> 4;
  const int cr = lane & 15;

  const u16* Abase;
  {
    int r = wv * 8 + (lane >> 3);
    int rr = m0 + r;
    if (rr > Mloc - 1) rr = Mloc - 1;
    long long grow = GATHER ? (long long)slots[goff + rr] : (long long)rr;
    Abase = Ae + grow * (long long)lda + (((lane & 7) ^ sw3(r)) << 3);
  }
  auto stageA = [&](int bf, int k0) {
    gload16(Abase + k0, &As[bf][wv * 512]);
  };

  const int bn = tid & 63;
  const int kc = tid >> 6;
  const float* Bbase = Bp + (long long)(kc << 3) * ldb + n0 + bn;
  const int bws = bn * 64 + ((kc ^ sw3(bn)) << 3);

  float br[8];
  auto loadB = [&](int k0) {
    const float* p = Bbase + (long long)k0 * ldb;
    #pragma unroll
    for (int j = 0; j < 8; ++j) br[j] = p[(long long)j * ldb];
  };
  auto writeB = [&](int bf) {
    u16x8 o;
    #pragma unroll
    for (int j = 0; j < 8; ++j) o[j] = f2b(br[j]);
    *(u16x8*)(&Bs[bf][bws]) = o;
  };

  f32x4 acc[2];
  acc[0] = f32x4{0.f, 0.f, 0.f, 0.f};
  acc[1] = f32x4{0.f, 0.f, 0.f, 0.f};

  int aoff[2], asw[2];
  #pragma unroll
  for (int m = 0; m < 2; ++m) {
    int r = wm * 32 + m * 16 + cr;
    aoff[m] = r * 64; asw[m] = sw3(r);
  }
  const int bc = wn * 16 + cr;
  const int boff = bc * 64;
  const int bsw = sw3(bc);

  auto mfma_step = [&](int bf) {
    const u16* Ap = &As[bf][0];
    const u16* Bq = &Bs[bf][0];
    #pragma unroll
    for (int sub = 0; sub < 2; ++sub) {
      int ck = kg + sub * 4;
      bf16x8 af0 = __builtin_bit_cast(bf16x8, *(const u16x8*)(Ap + aoff[0] + ((ck ^ asw[0]) << 3)));
      bf16x8 af1 = __builtin_bit_cast(bf16x8, *(const u16x8*)(Ap + aoff[1] + ((ck ^ asw[1]) << 3)));
      bf16x8 bfr = __builtin_bit_cast(bf16x8, *(const u16x8*)(Bq + boff + ((ck ^ bsw) << 3)));
      acc[0] = __builtin_amdgcn_mfma_f32_16x16x32_bf16(af0, bfr, acc[0], 0, 0, 0);
      acc[1] = __builtin_amdgcn_mfma_f32_16x16x32_bf16(af1, bfr, acc[1], 0, 0, 0);
    }
  };

  loadB(0);
  stageA(0, 0);
  writeB(0);
  __syncthreads();

  int buf = 0;
  for (int ks = 0; ks < K; ks += 64) {
    bool more = (ks + 64) < K;
    if (more) { loadB(ks + 64); stageA(buf ^ 1, ks + 64); }
    mfma_step(buf);
    if (more) writeB(buf ^ 1);
    __syncthreads();
    buf ^= 1;
  }

  const int rq = lane >> 4;
  #pragma unroll
  for (int m = 0; m < 2; ++m) {
    #pragma unroll
    for (int j = 0; j < 4; ++j) {
      int row = m0 + wm * 32 + m * 16 + rq * 4 + j;
      if (row >= Mloc) continue;
      int col = n0 + wn * 16 + cr;
      if constexpr (EPI == 0) {
        Op[(long long)(goff + row) * NW + col] = acc[m][j];
      } else {
        int tok = slots[goff + row];
        float wgt = slotw[goff + row];
        atomicAdd(Op + (long long)tok * NW + col, wgt * acc[m][j]);
      }
    }
  }
}

// ---------------------------------------------------------------------------
// Dense GEMM: M64 x N128 x BK32, 512 threads.
// EPI: 0 bf16 | 1 bf16*alpha | 2 f32 res1+acc | 5 f32 res1+acc dual-store
//      (Cf and Cf2) | 6 atomicAdd acc into Cf.
// ---------------------------------------------------------------------------
template<typename TB, int EPI, int CAUSAL>
__global__ __launch_bounds__(512, 8) void dense_gemm_k(
    const u16* __restrict__ A, const TB* __restrict__ B,
    u16* __restrict__ Cb, float* __restrict__ Cf, float* __restrict__ Cf2,
    const float* __restrict__ res1,
    int K, int lda, int ldb, int ldc, float alpha,
    long long sAz, long long sBz, long long sCz, int bdivz)
{
  __shared__ u16 As[2][64 * 32];
  __shared__ u16 Bs[2][128 * 32];

  const int m0 = blockIdx.y * 64;
  const int n0 = blockIdx.x * 128;
  if (CAUSAL == 1 && n0 > m0 + 63) return;
  const long long z = blockIdx.z;
  const u16* Ae = A + z * sAz;
  const TB* Be = B + (long long)(z / bdivz) * sBz;
  u16* Cwb = Cb ? Cb + z * sCz : nullptr;

  int kend = K;
  if (CAUSAL == 2) { int ke = m0 + 64; if (ke < kend) kend = ke; }

  const int tid = threadIdx.x;
  const int lane = tid & 63;
  const int wv = tid >> 6;
  const int wm = wv >> 2, wn = wv & 3;

  const u16* Abase = nullptr;
  if (wv < 4) {
    int r = wv * 16 + (lane >> 2);
    Abase = Ae + (long long)(m0 + r) * lda + (((lane & 3) ^ s2(r)) << 3);
  }
  auto stageA = [&](int bf, int k0) {
    if (wv < 4) gload16(Abase + k0, &As[bf][wv * 512]);
  };

  const u16* Bu16base = nullptr;
  const float* Bf32base = nullptr;
  int bws = 0;
  if constexpr (sizeof(TB) == 2) {
    int r = wv * 16 + (lane >> 2);
    Bu16base = (const u16*)Be + (long long)(n0 + r) * ldb + (((lane & 3) ^ s2(r)) << 3);
  } else {
    int bn = tid >> 2, bkq = tid & 3;
    Bf32base = (const float*)Be + (long long)(n0 + bn) * ldb + (bkq << 3);
    bws = bn * 32 + ((bkq ^ s2(bn)) << 3);
  }
  float br[8];
  auto loadB = [&](int k0) {
    const float* p = Bf32base + k0;
    float4 a = *(const float4*)p;
    float4 b = *(const float4*)(p + 4);
    br[0] = a.x; br[1] = a.y; br[2] = a.z; br[3] = a.w;
    br[4] = b.x; br[5] = b.y; br[6] = b.z; br[7] = b.w;
  };
  auto writeB = [&](int bf) {
    u16x8 o;
    #pragma unroll
    for (int j = 0; j < 8; ++j) o[j] = f2b(br[j]);
    *(u16x8*)(&Bs[bf][bws]) = o;
  };
  auto stageBu = [&](int bf, int k0) {
    gload16(Bu16base + k0, &Bs[bf][wv * 512]);
  };

  f32x4 acc[2][2];
  #pragma unroll
  for (int m = 0; m < 2; ++m)
    #pragma unroll
    for (int n = 0; n < 2; ++n)
      acc[m][n] = f32x4{0.f, 0.f, 0.f, 0.f};

  const int kg = lane >> 4;
  const int cr = lane & 15;

  int aoff[2], boff[2];
  #pragma unroll
  for (int m = 0; m < 2; ++m) {
    int r = wm * 32 + m * 16 + cr;
    aoff[m] = r * 32 + ((kg ^ s2(r)) << 3);
  }
  #pragma unroll
  for (int n = 0; n < 2; ++n) {
    int c = wn * 32 + n * 16 + cr;
    boff[n] = c * 32 + ((kg ^ s2(c)) << 3);
  }

  if constexpr (sizeof(TB) == 4) {
    loadB(0); stageA(0, 0); writeB(0);
  } else {
    stageA(0, 0); stageBu(0, 0);
  }
  __syncthreads();

  int buf = 0;
  for (int ks = 0; ks < kend; ks += 32) {
    bool more = (ks + 32) < kend;
    if (more) {
      if constexpr (sizeof(TB) == 4) { loadB(ks + 32); stageA(buf ^ 1, ks + 32); }
      else { stageA(buf ^ 1, ks + 32); stageBu(buf ^ 1, ks + 32); }
    }
    const u16* Ap = &As[buf][0];
    const u16* Bq = &Bs[buf][0];
    bf16x8 af[2], bfr[2];
    #pragma unroll
    for (int m = 0; m < 2; ++m)
      af[m] = __builtin_bit_cast(bf16x8, *(const u16x8*)(Ap + aoff[m]));
    #pragma unroll
    for (int n = 0; n < 2; ++n)
      bfr[n] = __builtin_bit_cast(bf16x8, *(const u16x8*)(Bq + boff[n]));
    #pragma unroll
    for (int m = 0; m < 2; ++m)
      #pragma unroll
      for (int n = 0; n < 2; ++n)
        acc[m][n] = __builtin_amdgcn_mfma_f32_16x16x32_bf16(af[m], bfr[n], acc[m][n], 0, 0, 0);
    if constexpr (sizeof(TB) == 4) { if (more) writeB(buf ^ 1); }
    __syncthreads();
    buf ^= 1;
  }

  const int rq = lane >> 4;
  #pragma unroll
  for (int m = 0; m < 2; ++m) {
    #pragma unroll
    for (int j = 0; j < 4; ++j) {
      int row = m0 + wm * 32 + m * 16 + rq * 4 + j;
      #pragma unroll
      for (int n = 0; n < 2; ++n) {
        int col = n0 + wn * 32 + n * 16 + cr;
        float v = acc[m][n][j];
        long long o = (long long)row * ldc + col;
        if constexpr (EPI == 0) {
          Cwb[o] = f2b(v);
        } else if constexpr (EPI == 1) {
          Cwb[o] = f2b(v * alpha);
        } else if constexpr (EPI == 2) {
          Cf[o] = res1[o] + v;
        } else if constexpr (EPI == 5) {
          float val = res1[o] + v;
          Cf[o] = val;
          Cf2[o] = val;
        } else {
          atomicAdd(&Cf[o], v);
        }
      }
    }
  }
}

// ---------------------------------------------------------------------------
__global__ __launch_bounds__(256) void vtrans_k(const u16* __restrict__ v_r,
                                                u16* __restrict__ v_t) {
  __shared__ u16 t[64][72];
  int kv = blockIdx.z;
  int s0 = blockIdx.x * 64, d0 = blockIdx.y * 64;
  int tid = threadIdx.x;
  int sr = tid >> 2, dq = (tid & 3) * 16;
  const u16* src = v_r + ((long long)kv * T_ + s0 + sr) * HD_ + d0 + dq;
  *(u16x8*)&t[sr][dq] = *(const u16x8*)src;
  *(u16x8*)&t[sr][dq + 8] = *(const u16x8*)(src + 8);
  __syncthreads();
  int dr = tid >> 2, sq = (tid & 3) * 16;
  u16* dst = v_t + ((long long)kv * HD_ + d0 + dr) * T_ + s0 + sq;
  u16x8 o0, o1;
  #pragma unroll
  for (int j = 0; j < 8; ++j) { o0[j] = t[sq + j][dr]; o1[j] = t[sq + 8 + j][dr]; }
  *(u16x8*)dst = o0;
  *(u16x8*)(dst + 8) = o1;
}

// ---------------------------------------------------------------------------
__global__ __launch_bounds__(256) void rmsnorm_k(const float* __restrict__ x,
                                                 const float* __restrict__ w,
                                                 u16* __restrict__ outb,
                                                 float* __restrict__ outf) {
  int t = blockIdx.x;
  int tid = threadIdx.x;
  const float* xr = x + (long long)t * H_;
  float4 a = *(const float4*)(xr + tid * 8);
  float4 b = *(const float4*)(xr + tid * 8 + 4);
  float ss = a.x * a.x + a.y * a.y + a.z * a.z + a.w * a.w +
             b.x * b.x + b.y * b.y + b.z * b.z + b.w * b.w;
  #pragma unroll
  for (int o = 32; o; o >>= 1) ss += __shfl_down(ss, o);
  __shared__ float red[4];
  if ((tid & 63) == 0) red[tid >> 6] = ss;
  __syncthreads();
  float sc = rsqrtf((red[0] + red[1] + red[2] + red[3]) * (1.0f / H_) + EPS_);
  float vo[8] = {a.x, a.y, a.z, a.w, b.x, b.y, b.z, b.w};
  const float* wr = w + tid * 8;
  u16x8 ob;
  #pragma unroll
  for (int q = 0; q < 8; ++q) {
    float val = vo[q] * sc * wr[q];
    ob[q] = f2b(val);
    if (outf) outf[(long long)t * H_ + tid * 8 + q] = val;
  }
  *(u16x8*)(outb + (long long)t * H_ + tid * 8) = ob;
}

__global__ __launch_bounds__(256) void rope_k(const u16* __restrict__ qkv,
                                              const int* __restrict__ pos,
                                              u16* __restrict__ q_r,
                                              u16* __restrict__ k_r,
                                              u16* __restrict__ v_r) {
  int t = blockIdx.x;
  int tid = threadIdx.x;
  float p = (float)pos[t];
  const u16* row = qkv + (long long)t * QKVN_;
  const float cfac = logf(THETA_) * (1.0f / 64.0f);
  #pragma unroll
  for (int it = 0; it < 4; ++it) {
    int item = it * 256 + tid;
    int h = item >> 6, d = item & 63;
    float inv = expf(-cfac * (float)d);
    float ang = p * inv;
    float c = cosf(ang), s = sinf(ang);
    float x1v = b2f(row[h * 128 + d]);
    float x2v = b2f(row[h * 128 + 64 + d]);
    u16* dst = q_r + ((long long)h * T_ + t) * HD_;
    dst[d] = f2b(x1v * c - x2v * s);
    dst[d + 64] = f2b(x1v * s + x2v * c);
  }
  {
    int item = tid;
    int kv = item >> 6, d = item & 63;
    float inv = expf(-cfac * (float)d);
    float ang = p * inv;
    float c = cosf(ang), s = sinf(ang);
    float x1v = b2f(row[NH_ * HD_ + kv * 128 + d]);
    float x2v = b2f(row[NH_ * HD_ + kv * 128 + 64 + d]);
    u16* dst = k_r + ((long long)kv * T_ + t) * HD_;
    dst[d] = f2b(x1v * c - x2v * s);
    dst[d + 64] = f2b(x1v * s + x2v * c);
  }
  #pragma unroll
  for (int it = 0; it < 2; ++it) {
    int item = it * 256 + tid;
    int kv = item >> 7, d = item & 127;
    v_r[((long long)kv * T_ + t) * HD_ + d] = row[(NH_ + NKV_) * HD_ + kv * 128 + d];
  }
}

// 4 rows per 256-thread block; one wave per row; u16x8 vectorized.
__global__ __launch_bounds__(256) void softmax2_k(u16* __restrict__ P) {
  int wv = threadIdx.x >> 6, lane = threadIdx.x & 63;
  int r = blockIdx.x * 4 + wv;
  int h = r >> 10, i = r & 1023;
  u16* row = P + ((long long)h * T_ + i) * T_;
  int n = i + 1;
  float v[16];
  float mx = -1e30f;
  #pragma unroll
  for (int c = 0; c < 2; ++c) {
    int j0 = (c * 64 + lane) * 8;
    u16x8 xv = *(const u16x8*)(row + j0);
    #pragma unroll
    for (int q = 0; q < 8; ++q) {
      float s = (j0 + q < n) ? b2f(xv[q]) : -1e30f;
      v[c * 8 + q] = s;
      mx = fmaxf(mx, s);
    }
  }
  #pragma unroll
  for (int o = 32; o; o >>= 1) mx = fmaxf(mx, __shfl_xor(mx, o));
  float sum = 0.f;
  #pragma unroll
  for (int c = 0; c < 2; ++c) {
    #pragma unroll
    for (int q = 0; q < 8; ++q) {
      int j = (c * 64 + lane) * 8 + q;
      float e = (j < n) ? __expf(v[c * 8 + q] - mx) : 0.f;
      v[c * 8 + q] = e;
      sum += e;
    }
  }
  #pragma unroll
  for (int o = 32; o; o >>= 1) sum += __shfl_xor(sum, o);
  float inv = 1.f / sum;
  #pragma unroll
  for (int c = 0; c < 2; ++c) {
    int j0 = (c * 64 + lane) * 8;
    u16x8 ov;
    #pragma unroll
    for (int q = 0; q < 8; ++q) ov[q] = f2b(v[c * 8 + q] * inv);
    *(u16x8*)(row + j0) = ov;
  }
}

__global__ __launch_bounds__(256) void router2_k(const float* __restrict__ h2,
                                                 const float* __restrict__ wr,
                                                 float* __restrict__ logits) {
  __shared__ float hrow[H_];
  int t = blockIdx.x;
  int tid = threadIdx.x;
  float4 a = *(const float4*)(h2 + (long long)t * H_ + tid * 8);
  float4 b = *(const float4*)(h2 + (long long)t * H_ + tid * 8 + 4);
  *(float4*)&hrow[tid * 8] = a;
  *(float4*)&hrow[tid * 8 + 4] = b;
  __syncthreads();
  int wv = tid >> 6, lane = tid & 63;
  #pragma unroll
  for (int ei = 0; ei < 8; ++ei) {
    int e = wv * 8 + ei;
    const float* wrow = wr + (long long)e * H_;
    float s = 0.f;
    #pragma unroll
    for (int it = 0; it < 8; ++it) {
      int k = it * 256 + lane * 4;
      float4 w4 = *(const float4*)(wrow + k);
      s += hrow[k] * w4.x + hrow[k + 1] * w4.y + hrow[k + 2] * w4.z + hrow[k + 3] * w4.w;
    }
    #pragma unroll
    for (int o = 32; o; o >>= 1) s += __shfl_xor(s, o);
    if (lane == 0) logits[t * E_ + e] = s;
  }
}

__global__ __launch_bounds__(256) void topk_k(const float* __restrict__ logits,
                                              int* __restrict__ topi,
                                              float* __restrict__ topw) {
  int t = blockIdx.x * 256 + threadIdx.x;
  if (t >= T_) return;
  float l[E_];
  #pragma unroll
  for (int e = 0; e < E_; ++e) l[e] = logits[t * E_ + e];
  int sel[TOPK_];
  float sv[TOPK_];
  unsigned used = 0;
  for (int j = 0; j < TOPK_; ++j) {
    float best = -1e30f;
    int bi = 0;
    for (int e = 0; e < E_; ++e) {
      if (used & (1u << e)) continue;
      if (l[e] > best) { best = l[e]; bi = e; }
    }
    used |= 1u << bi;
    sel[j] = bi;
    sv[j] = best;
  }
  float mx = sv[0];
  float s = 0.f;
  #pragma unroll
  for (int j = 0; j < TOPK_; ++j) { sv[j] = __expf(sv[j] - mx); s += sv[j]; }
  float inv = 1.f / s;
  #pragma unroll
  for (int j = 0; j < TOPK_; ++j) {
    topi[t * TOPK_ + j] = sel[j];
    topw[t * TOPK_ + j] = sv[j] * inv;
  }
}

__global__ __launch_bounds__(256) void hist_k(const int* __restrict__ topi, int* __restrict__ cnt) {
  int idx = blockIdx.x * 256 + threadIdx.x;
  if (idx < T_ * TOPK_) atomicAdd(&cnt[topi[idx]], 1);
}

__global__ __launch_bounds__(64) void scan_k(const int* __restrict__ cnt,
                                             int* __restrict__ eoff,
                                             int* __restrict__ cursor,
                                             int* __restrict__ tpre) {
  if (threadIdx.x == 0) {
    int s = 0, tt = 0;
    for (int e = 0; e < E_; ++e) {
      eoff[e] = s; cursor[e] = s; tpre[e] = tt;
      tt += (cnt[e] + 63) >> 6;
      s += cnt[e];
    }
    eoff[E_] = s; tpre[E_] = tt;
  }
}

__global__ __launch_bounds__(256) void scatter_k(const int* __restrict__ topi,
                                                 const float* __restrict__ topw,
                                                 int* __restrict__ cursor,
                                                 int* __restrict__ slots,
                                                 float* __restrict__ slotw) {
  int idx = blockIdx.x * 256 + threadIdx.x;
  if (idx >= T_ * TOPK_) return;
  int e = topi[idx];
  int pos = atomicAdd(&cursor[e], 1);
  slots[pos] = idx >> 2;
  slotw[pos] = topw[idx];
}

__global__ __launch_bounds__(256) void silumul_f_k(const float* __restrict__ g,
                                                   const float* __restrict__ u,
                                                   u16* __restrict__ a) {
  long long idx = ((long long)blockIdx.x * 256 + threadIdx.x) * 8;
  float4 g0 = *(const float4*)(g + idx);
  float4 g1 = *(const float4*)(g + idx + 4);
  float4 u0 = *(const float4*)(u + idx);
  float4 u1 = *(const float4*)(u + idx + 4);
  float gv[8] = {g0.x, g0.y, g0.z, g0.w, g1.x, g1.y, g1.z, g1.w};
  float uv[8] = {u0.x, u0.y, u0.z, u0.w, u1.x, u1.y, u1.z, u1.w};
  u16x8 o;
  #pragma unroll
  for (int q = 0; q < 8; ++q) {
    float x = gv[q];
    float sl = x / (1.f + __expf(-x));
    o[q] = f2b(sl * uv[q]);
  }
  *(u16x8*)(a + idx) = o;
}

__global__ __launch_bounds__(256) void sharedact_k(const u16* __restrict__ gu,
                                                   u16* __restrict__ act) {
  long long idx = ((long long)blockIdx.x * 256 + threadIdx.x) * 8;
  long long t = idx >> 10;
  int i = (int)(idx & 1023);
  const u16* row = gu + t * (2 * I_);
  u16x8 g = *(const u16x8*)(row + i);
  u16x8 u = *(const u16x8*)(row + I_ + i);
  u16x8 o;
  #pragma unroll
  for (int q = 0; q < 8; ++q) {
    float x = b2f(g[q]);
    float y = b2f(u[q]);
    float sl = x / (1.f + __expf(-x));
    o[q] = f2b(sl * y);
  }
  *(u16x8*)(act + t * I_ + i) = o;
}

// ---------------------------------------------------------------------------
extern "C" void kernel_launch(void* const* d_in, const int* in_sizes, int n_in,
                              void* d_out, int out_size, void* d_ws, size_t ws_size,
                              hipStream_t stream) {
  const float* x        = (const float*)d_in[0];
  const int* positions  = (const int*)d_in[1];
  const float* w_rms1   = (const float*)d_in[2];
  const float* w_rms2   = (const float*)d_in[3];
  const float* w_qkv    = (const float*)d_in[4];
  const float* w_o      = (const float*)d_in[5];
  const float* w_router = (const float*)d_in[6];
  const float* w1       = (const float*)d_in[7];
  const float* w3       = (const float*)d_in[8];
  const float* w2       = (const float*)d_in[9];
  const float* ws_gu    = (const float*)d_in[10];
  const float* ws_dn    = (const float*)d_in[11];
  float* out = (float*)d_out;

  char* ws = (char*)d_ws;
  size_t off = 0;
  auto alloc = [&](size_t bytes) {
    size_t o = off;
    off = (off + bytes + 255) & ~(size_t)255;
    return (void*)(ws + o);
  };
  u16*  h1b     = (u16*)alloc((size_t)T_ * H_ * 2);
  u16*  qkvb    = (u16*)alloc((size_t)T_ * QKVN_ * 2);
  u16*  q_r     = (u16*)alloc((size_t)NH_ * T_ * HD_ * 2);
  u16*  k_r     = (u16*)alloc((size_t)NKV_ * T_ * HD_ * 2);
  u16*  v_r     = (u16*)alloc((size_t)NKV_ * T_ * HD_ * 2);
  u16*  v_t     = (u16*)alloc((size_t)NKV_ * HD_ * T_ * 2);
  u16*  scoresP = (u16*)alloc((size_t)NH_ * T_ * T_ * 2);   // reused as g/u f32
  u16*  o_attn  = (u16*)alloc((size_t)T_ * H_ * 2);
  float* x1     = (float*)alloc((size_t)T_ * H_ * 4);
  float* h2f    = (float*)alloc((size_t)T_ * H_ * 4);
  u16*  h2b     = (u16*)alloc((size_t)T_ * H_ * 2);
  u16*  gub     = (u16*)alloc((size_t)T_ * 2 * I_ * 2);
  u16*  actsh   = (u16*)alloc((size_t)T_ * I_ * 2);
  float* logits = (float*)alloc((size_t)T_ * E_ * 4);
  int*  topi    = (int*)alloc((size_t)T_ * TOPK_ * 4);
  float* topw   = (float*)alloc((size_t)T_ * TOPK_ * 4);
  int*  cnt     = (int*)alloc(E_ * 4);
  int*  eoffp   = (int*)alloc((E_ + 1) * 4);
  int*  cursor  = (int*)alloc(E_ * 4);
  int*  tpre    = (int*)alloc((E_ + 1) * 4);
  int*  slots   = (int*)alloc((size_t)T_ * TOPK_ * 4);
  float* slotw  = (float*)alloc((size_t)T_ * TOPK_ * 4);
  u16*  a_g     = (u16*)alloc((size_t)T_ * TOPK_ * I_ * 2);

  float* g_f32 = (float*)scoresP;
  float* u_f32 = g_f32 + (size_t)T_ * TOPK_ * I_;

  hipMemsetAsync(cnt, 0, E_ * 4, stream);

  // 1. h = rmsnorm(x, w_rms1)
  rmsnorm_k<<<T_, 256, 0, stream>>>(x, w_rms1, h1b, nullptr);

  // 2. qkv = h @ w_qkv.T
  dense_gemm_k<float, 0, 0><<<dim3(24, 16, 1), 512, 0, stream>>>(
      h1b, w_qkv, qkvb, nullptr, nullptr, nullptr,
      H_, H_, H_, QKVN_, 1.f, 0, 0, 0, 1);

  // 3. RoPE + unpack; V transpose
  rope_k<<<T_, 256, 0, stream>>>(qkvb, positions, q_r, k_r, v_r);
  vtrans_k<<<dim3(16, 2, 4), 256, 0, stream>>>(v_r, v_t);

  // 4. scores = scale * q @ k^T per head (causal skip)
  dense_gemm_k<u16, 1, 1><<<dim3(8, 16, NH_), 512, 0, stream>>>(
      q_r, k_r, scoresP, nullptr, nullptr, nullptr,
      HD_, HD_, HD_, T_, SCALE_,
      (long long)T_ * HD_, (long long)T_ * HD_, (long long)T_ * T_, NH_ / NKV_);

  // 5. masked softmax rows (4 rows per 256-thread block)
  softmax2_k<<<NH_ * T_ / 4, 256, 0, stream>>>(scoresP);

  // 6. o = P @ V per head
  dense_gemm_k<u16, 0, 2><<<dim3(1, 16, NH_), 512, 0, stream>>>(
      scoresP, v_t, o_attn, nullptr, nullptr, nullptr,
      T_, T_, T_, H_, 1.f,
      (long long)T_ * T_, (long long)HD_ * T_, (long long)HD_, NH_ / NKV_);

  // 7. x1 = x + o @ w_o.T ; out = x1 (dual store pre-inits out for atomics)
  dense_gemm_k<float, 5, 0><<<dim3(16, 16, 1), 512, 0, stream>>>(
      o_attn, w_o, nullptr, x1, out, x,
      H_, H_, H_, H_, 1.f, 0, 0, 0, 1);

  // 8. h2 = rmsnorm(x1, w_rms2)
  rmsnorm_k<<<T_, 256, 0, stream>>>(x1, w_rms2, h2b, h2f);

  // 9. router (block-per-token) + top-k + grouping
  router2_k<<<T_, 256, 0, stream>>>(h2f, w_router, logits);
  topk_k<<<4, 256, 0, stream>>>(logits, topi, topw);
  hist_k<<<16, 256, 0, stream>>>(topi, cnt);
  scan_k<<<1, 64, 0, stream>>>(cnt, eoffp, cursor, tpre);
  scatter_k<<<16, 256, 0, stream>>>(topi, topw, cursor, slots, slotw);

  // 10. fused grouped up (compact static grid, N64 x BK64, plain stores)
  moe_gemm_k<0, true><<<3072, 512, 0, stream>>>(
      h2b, w1, w3, g_f32, u_f32,
      I_, H_, I_, H_, eoffp, tpre, slots, nullptr, (long long)H_ * I_);
  silumul_f_k<<<(T_ * TOPK_ * I_) / (256 * 8), 256, 0, stream>>>(g_f32, u_f32, a_g);

  // 11. shared expert gu + act (independent of down; fills gap before it)
  dense_gemm_k<float, 0, 0><<<dim3(16, 16, 1), 512, 0, stream>>>(
      h2b, ws_gu, gub, nullptr, nullptr, nullptr,
      H_, H_, H_, 2 * I_, 1.f, 0, 0, 0, 1);
  sharedact_k<<<(T_ * I_) / (256 * 8), 256, 0, stream>>>(gub, actsh);

  // 12. grouped down: out += routed (atomics; out pre-set to x1)
  moe_gemm_k<1, false><<<3072, 512, 0, stream>>>(
      a_g, w2, nullptr, out, nullptr,
      H_, I_, H_, I_, eoffp, tpre, slots, slotw, (long long)I_ * H_);

  // 13. out += actsh @ ws_down.T (atomicAdd; independent of 12 -> tail overlap)
  dense_gemm_k<float, 6, 0><<<dim3(16, 16, 1), 512, 0, stream>>>(
      actsh, ws_dn, nullptr, out, nullptr, nullptr,
      I_, I_, I_, H_, 1.f, 0, 0, 0, 1);
}